// Round 4
// baseline (2534.981 us; speedup 1.0000x reference)
//
#include <hip/hip_runtime.h>

#define BATCH 512
#define NN    32
#define NVT   32
#define HS    501
#define VS    533
#define KP    512

typedef short bf16x8 __attribute__((ext_vector_type(8)));
typedef float f32x4  __attribute__((ext_vector_type(4)));

__device__ __forceinline__ unsigned short f2bf(float f) {
    unsigned int u = __float_as_uint(f);
    u += 0x7fffu + ((u >> 16) & 1u);
    return (unsigned short)(u >> 16);
}
__device__ __forceinline__ float bf2f(unsigned short s) {
    return __uint_as_float(((unsigned int)s) << 16);
}
__device__ __forceinline__ float sigmoidf_(float x) { return 1.0f / (1.0f + __expf(-x)); }
__device__ __forceinline__ float tanhf_(float x)    { return 1.0f - 2.0f / (1.0f + __expf(2.0f * x)); }

// swizzled ushort index for [16][512] bf16 LDS tiles (row stride 1024B, XOR byte bits 4..6 with row&7)
// NOTE: for k-stepping use  idxus(row, k0) ^ (kk*32)  — the components are bit-disjoint, XOR not ADD.
__device__ __forceinline__ int idxus(int row, int k) {
    return (((row << 10) + (k << 1)) ^ ((row & 7) << 4)) >> 1;
}

#define N_WHH  (3 * KP * KP)
#define N_WGM  (2 * KP * KP)
#define N_GI   (3 * NVT * KP)
#define N_IDW  (2 * NN * KP)
#define N_WRT  (KP * NN)
#define N_TOT  (N_WHH + N_WGM + N_GI + N_IDW + N_WRT)

__global__ void prep_kernel(const float* __restrict__ W_hh, const float* __restrict__ Wg,
                            const float* __restrict__ Wm, const float* __restrict__ W_ih,
                            const float* __restrict__ b_ih, const float* __restrict__ b_hh,
                            const float* __restrict__ bg, const float* __restrict__ W_reg,
                            unsigned short* __restrict__ Whh_p, unsigned short* __restrict__ Wgm_p,
                            float* __restrict__ gi_tab, float* __restrict__ idw,
                            float* __restrict__ WregT)
{
    for (int i = blockIdx.x * blockDim.x + threadIdx.x; i < N_TOT; i += gridDim.x * blockDim.x) {
        int j = i;
        if (j < N_WHH) {
            int g = j >> 18, rem = j & (KP * KP - 1);
            int h = rem >> 9, k = rem & (KP - 1);
            float val = 0.0f;
            if (h < HS) {
                if (k < HS)        val = W_hh[(size_t)(g * HS + h) * HS + k];
                else if (k == HS)  val = b_hh[g * HS + h];   // bias folded at k=501
            }
            Whh_p[j] = f2bf(val);
            continue;
        }
        j -= N_WHH;
        if (j < N_WGM) {
            int m = j >> 18, rem = j & (KP * KP - 1);
            int h = rem >> 9, k = rem & (KP - 1);
            const float* src = m ? Wm : Wg;
            Wgm_p[j] = (h < HS && k < HS) ? f2bf(src[(size_t)h * VS + k]) : (unsigned short)0;
            continue;
        }
        j -= N_WGM;
        if (j < N_GI) {
            int g = j >> 14, typ = (j >> 9) & 31, h = j & (KP - 1);
            gi_tab[j] = (h < HS) ? (W_ih[(size_t)(g * HS + h) * NVT + typ] + b_ih[g * HS + h]) : 0.0f;
            continue;
        }
        j -= N_GI;
        if (j < N_IDW) {
            int m = j >> 14, v = (j >> 9) & 31, h = j & (KP - 1);
            float val = 0.0f;
            if (h < HS)
                val = m ? Wm[(size_t)h * VS + HS + v]
                        : (Wg[(size_t)h * VS + HS + v] + bg[h]);
            idw[j] = val;
            continue;
        }
        j -= N_IDW;
        {
            int k = j >> 5, ii = j & 31;
            WregT[j] = (k < HS) ? W_reg[(size_t)ii * HS + k] : 0.0f;
        }
    }
}

// Persistent kernel: 32 blocks x 512 threads; block owns 16 batch rows for all 32 steps.
__global__ __launch_bounds__(512, 2) void dvae_kernel(
    const unsigned short* __restrict__ Whh,   // [3*512][512] bf16 (k=501 = b_hh)
    const unsigned short* __restrict__ Wgm,   // [2*512][512] bf16
    const float* __restrict__ gi_tab,         // [3][32][512]  W_ih[:,typ]+b_ih
    const float* __restrict__ idw,            // [2][32][512]  id-col (+bg)
    const float* __restrict__ WregT,          // [512][32]
    const float* __restrict__ b_reg,          // [32]
    const int*   __restrict__ types,          // [512][32]
    const float* __restrict__ adj,            // [512][32][32]
    unsigned short* __restrict__ Gbuf,        // [32 blk][32 u][16 b][512 h] bf16
    float* __restrict__ HvF,                  // [512][512]
    float* __restrict__ out)                  // [512][32]
{
    __shared__ unsigned short MsgbL[16 * 512];   // swizzled bf16 (MFMA A operand)
    __shared__ unsigned short HvbL[16 * 512];    // swizzled bf16
    __shared__ unsigned short GvL[16 * 512];     // swizzled bf16
    __shared__ float          MsgF[16 * 512];    // f32 mirror of Msg (exact GRU blend)
    __shared__ unsigned int   adjb[16 * 32];     // [b][u] bit v'
    __shared__ int            typs[16 * 32];     // [b][v]

    const int t   = threadIdx.x;
    const int bb  = blockIdx.x * 16;
    const int lane = t & 63, w = t >> 6;
    const int c16 = lane & 15, kg = lane >> 4;

    // stage adjacency bitmask + types (one thread per (b,u))
    {
        const int b = t >> 5, u = t & 31;
        const float* arow = adj + ((size_t)(bb + b) * NN + u) * NN;
        unsigned int bits = 0;
        #pragma unroll
        for (int vp = 0; vp < 32; vp++) bits |= (arow[vp] != 0.0f ? 1u : 0u) << vp;
        adjb[b * 32 + u] = bits;
        typs[b * 32 + u] = types[(bb + b) * NN + u];
    }
    // owner init: Msg = 0 with bias-1 at k=501
    {
        const int b = t >> 5, hb16 = (t & 31) * 16;
        bf16x8 z0 = {0,0,0,0,0,0,0,0};
        bf16x8 z1 = {0,0,0,0,0,0,0,0};
        if (hb16 == 496) z0[5] = (short)0x3F80;   // k=501 bias column = 1.0
        *(bf16x8*)&MsgbL[idxus(b, hb16)]     = z0;
        *(bf16x8*)&MsgbL[idxus(b, hb16 + 8)] = z1;
        #pragma unroll
        for (int x = 0; x < 16; x++) MsgF[b * KP + hb16 + x] = 0.0f;
        if (hb16 == 496) MsgF[b * KP + 501] = 1.0f;
    }
    __syncthreads();

    unsigned short* Gblk = Gbuf + (size_t)blockIdx.x * NN * 16 * KP;

    for (int v = 0; v < NN; v++) {
        // ---- phase A: gh[16 x 1536] = Msgb @ Whh^T ; wave w owns h16 tiles w*4..w*4+3, gates 0..2
        f32x4 acc[3][4];
        #pragma unroll
        for (int g = 0; g < 3; g++)
            #pragma unroll
            for (int q = 0; q < 4; q++) acc[g][q] = (f32x4){0.f,0.f,0.f,0.f};

        {
            const int aBase = idxus(c16, kg * 8);
            const unsigned short* wBase[3][4];
            #pragma unroll
            for (int g = 0; g < 3; g++)
                #pragma unroll
                for (int q = 0; q < 4; q++)
                    wBase[g][q] = Whh + ((size_t)((g * 32 + w * 4 + q) * 16 + c16) * KP + kg * 8);
            #pragma unroll 2
            for (int kk = 0; kk < 16; kk++) {
                bf16x8 af = *(const bf16x8*)&MsgbL[aBase ^ (kk * 32)];   // XOR-step (bit-disjoint)
                #pragma unroll
                for (int g = 0; g < 3; g++)
                    #pragma unroll
                    for (int q = 0; q < 4; q++) {
                        bf16x8 wf = *(const bf16x8*)(wBase[g][q] + kk * 32);
                        acc[g][q] = __builtin_amdgcn_mfma_f32_16x16x32_bf16(af, wf, acc[g][q], 0, 0, 0);
                    }
            }
        }
        // epilogue A -> Hvb (and HvF at v=31)
        #pragma unroll
        for (int q = 0; q < 4; q++) {
            const int h = (w * 4 + q) * 16 + c16;
            const bool ok = (h < HS);
            #pragma unroll
            for (int j = 0; j < 4; j++) {
                const int bl = kg * 4 + j;
                float hv = 0.0f;
                if (ok) {
                    const int typ = typs[bl * 32 + v];
                    const float gr = gi_tab[(size_t)(0 * 32 + typ) * KP + h];
                    const float gz = gi_tab[(size_t)(1 * 32 + typ) * KP + h];
                    const float gn = gi_tab[(size_t)(2 * 32 + typ) * KP + h];
                    const float hmsg = MsgF[bl * KP + h];
                    const float r = sigmoidf_(gr + acc[0][q][j]);
                    const float z = sigmoidf_(gz + acc[1][q][j]);
                    const float n = tanhf_(gn + r * acc[2][q][j]);
                    hv = (1.0f - z) * n + z * hmsg;
                }
                HvbL[idxus(bl, h)] = f2bf(hv);
                if (v == NN - 1) HvF[(size_t)(bb + bl) * KP + h] = hv;
            }
        }
        if (v == NN - 1) break;
        __syncthreads();

        // ---- phase B: z[16 x 1024] = Hvb @ Wgm^T ; wave w owns h16 tiles w*4..w*4+3, mats 0..1
        f32x4 acc2[2][4];
        #pragma unroll
        for (int m = 0; m < 2; m++)
            #pragma unroll
            for (int q = 0; q < 4; q++) acc2[m][q] = (f32x4){0.f,0.f,0.f,0.f};
        {
            const int aBase = idxus(c16, kg * 8);
            const unsigned short* wBase[2][4];
            #pragma unroll
            for (int m = 0; m < 2; m++)
                #pragma unroll
                for (int q = 0; q < 4; q++)
                    wBase[m][q] = Wgm + ((size_t)((m * 32 + w * 4 + q) * 16 + c16) * KP + kg * 8);
            #pragma unroll 2
            for (int kk = 0; kk < 16; kk++) {
                bf16x8 af = *(const bf16x8*)&HvbL[aBase ^ (kk * 32)];    // XOR-step
                #pragma unroll
                for (int m = 0; m < 2; m++)
                    #pragma unroll
                    for (int q = 0; q < 4; q++) {
                        bf16x8 wf = *(const bf16x8*)(wBase[m][q] + kk * 32);
                        acc2[m][q] = __builtin_amdgcn_mfma_f32_16x16x32_bf16(af, wf, acc2[m][q], 0, 0, 0);
                    }
            }
        }
        // epilogue B -> GvL
        #pragma unroll
        for (int q = 0; q < 4; q++) {
            const int h = (w * 4 + q) * 16 + c16;
            const bool ok = (h < HS);
            #pragma unroll
            for (int j = 0; j < 4; j++) {
                const int bl = kg * 4 + j;
                float gq = 0.0f;
                if (ok) {
                    const float zg = acc2[0][q][j] + idw[(size_t)(0 * 32 + v) * KP + h];
                    const float zm = acc2[1][q][j] + idw[(size_t)(1 * 32 + v) * KP + h];
                    gq = sigmoidf_(zg) * zm;
                }
                GvL[idxus(bl, h)] = f2bf(gq);
            }
        }
        __syncthreads();

        // ---- owners: persist G_v, build Msg_{v+1} (f32 + bf16 mirror)
        {
            const int b = t >> 5, hb16 = (t & 31) * 16;
            bf16x8 g0 = *(const bf16x8*)&GvL[idxus(b, hb16)];
            bf16x8 g1 = *(const bf16x8*)&GvL[idxus(b, hb16 + 8)];
            *(bf16x8*)&Gblk[(size_t)(v * 16 + b) * KP + hb16]     = g0;
            *(bf16x8*)&Gblk[(size_t)(v * 16 + b) * KP + hb16 + 8] = g1;

            float msg[16];
            #pragma unroll
            for (int x = 0; x < 16; x++) msg[x] = 0.0f;
            const unsigned int nxt = 1u << (v + 1);
            for (int u = 0; u <= v; u++) {
                if (adjb[b * 32 + u] & nxt) {
                    bf16x8 a0, a1;
                    if (u == v) { a0 = g0; a1 = g1; }
                    else {
                        a0 = *(const bf16x8*)&Gblk[(size_t)(u * 16 + b) * KP + hb16];
                        a1 = *(const bf16x8*)&Gblk[(size_t)(u * 16 + b) * KP + hb16 + 8];
                    }
                    #pragma unroll
                    for (int x = 0; x < 8; x++) {
                        msg[x]     += bf2f((unsigned short)a0[x]);
                        msg[x + 8] += bf2f((unsigned short)a1[x]);
                    }
                }
            }
            if (hb16 == 496) msg[5] = 1.0f;   // bias column k=501
            bf16x8 m0, m1;
            #pragma unroll
            for (int x = 0; x < 8; x++) { m0[x] = (short)f2bf(msg[x]); m1[x] = (short)f2bf(msg[x + 8]); }
            *(bf16x8*)&MsgbL[idxus(b, hb16)]     = m0;
            *(bf16x8*)&MsgbL[idxus(b, hb16 + 8)] = m1;
            #pragma unroll
            for (int x = 0; x < 16; x++) MsgF[b * KP + hb16 + x] = msg[x];
        }
        __syncthreads();
    }

    // ---- final: mu = HvF @ WregT + b_reg (block's 16 rows)
    __threadfence_block();
    __syncthreads();
    {
        const int b = t >> 5, i = t & 31;
        float s = b_reg[i];
        const float* hp = HvF + (size_t)(bb + b) * KP;
        #pragma unroll 4
        for (int k = 0; k < KP; k++) s += hp[k] * WregT[k * 32 + i];
        out[(bb + b) * 32 + i] = s;
    }
}

extern "C" void kernel_launch(void* const* d_in, const int* in_sizes, int n_in,
                              void* d_out, int out_size, void* d_ws, size_t ws_size,
                              hipStream_t stream) {
    const int*   node_types = (const int*)  d_in[0];
    const float* adj        = (const float*)d_in[1];
    const float* Wg         = (const float*)d_in[2];
    const float* bg         = (const float*)d_in[3];
    const float* Wm         = (const float*)d_in[4];
    const float* W_ih       = (const float*)d_in[5];
    const float* b_ih       = (const float*)d_in[6];
    const float* W_hh       = (const float*)d_in[7];
    const float* b_hh       = (const float*)d_in[8];
    const float* W_reg      = (const float*)d_in[9];
    const float* b_reg      = (const float*)d_in[10];
    float* out = (float*)d_out;

    char* p = (char*)d_ws;
    unsigned short* Whh_p = (unsigned short*)p; p += (size_t)N_WHH * 2;
    unsigned short* Wgm_p = (unsigned short*)p; p += (size_t)N_WGM * 2;
    float* gi_tab = (float*)p; p += (size_t)N_GI * 4;
    float* idw    = (float*)p; p += (size_t)N_IDW * 4;
    float* WregT  = (float*)p; p += (size_t)N_WRT * 4;
    float* HvF    = (float*)p; p += (size_t)BATCH * KP * 4;
    unsigned short* Gbuf = (unsigned short*)p; p += (size_t)32 * NN * 16 * KP * 2;

    prep_kernel<<<1024, 256, 0, stream>>>(W_hh, Wg, Wm, W_ih, b_ih, b_hh, bg, W_reg,
                                          Whh_p, Wgm_p, gi_tab, idw, WregT);
    dvae_kernel<<<32, 512, 0, stream>>>(Whh_p, Wgm_p, gi_tab, idw, WregT, b_reg,
                                        node_types, adj, Gbuf, HvF, out);
}

// Round 5
// 2493.978 us; speedup vs baseline: 1.0164x; 1.0164x over previous
//
#include <hip/hip_runtime.h>

#define BATCH 512
#define NN    32
#define NVT   32
#define HS    501
#define VS    533
#define KP    512

typedef short bf16x8 __attribute__((ext_vector_type(8)));
typedef float f32x4  __attribute__((ext_vector_type(4)));

__device__ __forceinline__ unsigned short f2bf(float f) {
    unsigned int u = __float_as_uint(f);
    u += 0x7fffu + ((u >> 16) & 1u);
    return (unsigned short)(u >> 16);
}
__device__ __forceinline__ float bf2f(unsigned short s) {
    return __uint_as_float(((unsigned int)s) << 16);
}
__device__ __forceinline__ float sigmoidf_(float x) { return 1.0f / (1.0f + __expf(-x)); }
__device__ __forceinline__ float tanhf_(float x)    { return 1.0f - 2.0f / (1.0f + __expf(2.0f * x)); }

// swizzled ushort index for [16][512] bf16 LDS tiles (row stride 1024B, XOR byte bits 4..6 with row&7)
// k-stepping: idxus(row,k0) ^ (kk*32) — linear components are bit-disjoint, XOR commutes with swizzle.
__device__ __forceinline__ int idxus(int row, int k) {
    return (((row << 10) + (k << 1)) ^ ((row & 7) << 4)) >> 1;
}

#define N_WHH  (3 * KP * KP)
#define N_WGM  (2 * KP * KP)
#define N_GI   (3 * NVT * KP)
#define N_IDW  (2 * NN * KP)
#define N_WRT  (KP * NN)
#define N_TOT  (N_WHH + N_WGM + N_GI + N_IDW + N_WRT)

__global__ void prep_kernel(const float* __restrict__ W_hh, const float* __restrict__ Wg,
                            const float* __restrict__ Wm, const float* __restrict__ W_ih,
                            const float* __restrict__ b_ih, const float* __restrict__ b_hh,
                            const float* __restrict__ bg, const float* __restrict__ W_reg,
                            unsigned short* __restrict__ Whh_p, unsigned short* __restrict__ Wgm_p,
                            float* __restrict__ gi_tab, float* __restrict__ idw,
                            float* __restrict__ WregT)
{
    for (int i = blockIdx.x * blockDim.x + threadIdx.x; i < N_TOT; i += gridDim.x * blockDim.x) {
        int j = i;
        if (j < N_WHH) {
            int g = j >> 18, rem = j & (KP * KP - 1);
            int h = rem >> 9, k = rem & (KP - 1);
            float val = 0.0f;
            if (h < HS) {
                if (k < HS)        val = W_hh[(size_t)(g * HS + h) * HS + k];
                else if (k == HS)  val = b_hh[g * HS + h];   // bias folded at k=501
            }
            Whh_p[j] = f2bf(val);
            continue;
        }
        j -= N_WHH;
        if (j < N_WGM) {
            int m = j >> 18, rem = j & (KP * KP - 1);
            int h = rem >> 9, k = rem & (KP - 1);
            const float* src = m ? Wm : Wg;
            Wgm_p[j] = (h < HS && k < HS) ? f2bf(src[(size_t)h * VS + k]) : (unsigned short)0;
            continue;
        }
        j -= N_WGM;
        if (j < N_GI) {
            int g = j >> 14, typ = (j >> 9) & 31, h = j & (KP - 1);
            gi_tab[j] = (h < HS) ? (W_ih[(size_t)(g * HS + h) * NVT + typ] + b_ih[g * HS + h]) : 0.0f;
            continue;
        }
        j -= N_GI;
        if (j < N_IDW) {
            int m = j >> 14, v = (j >> 9) & 31, h = j & (KP - 1);
            float val = 0.0f;
            if (h < HS)
                val = m ? Wm[(size_t)h * VS + HS + v]
                        : (Wg[(size_t)h * VS + HS + v] + bg[h]);
            idw[j] = val;
            continue;
        }
        j -= N_IDW;
        {
            int k = j >> 5, ii = j & 31;
            WregT[j] = (k < HS) ? W_reg[(size_t)ii * HS + k] : 0.0f;
        }
    }
}

// Persistent kernel: 32 blocks x 1024 threads (16 waves, 4/SIMD); block owns 16 batch rows.
__global__ __launch_bounds__(1024, 4) void dvae_kernel(
    const unsigned short* __restrict__ Whh,   // [3*512][512] bf16 (k=501 = b_hh)
    const unsigned short* __restrict__ Wgm,   // [2*512][512] bf16
    const float* __restrict__ gi_tab,         // [3][32][512]
    const float* __restrict__ idw,            // [2][32][512]
    const float* __restrict__ WregT,          // [512][32]
    const float* __restrict__ b_reg,          // [32]
    const int*   __restrict__ types,          // [512][32]
    const float* __restrict__ adj,            // [512][32][32]
    unsigned short* __restrict__ Gbuf,        // [32 blk][32 u][16 b][512 h] bf16
    float* __restrict__ HvF,                  // [512][512]
    float* __restrict__ out)                  // [512][32]
{
    __shared__ unsigned short MsgbL[16 * 512];   // swizzled bf16 (MFMA A operand)
    __shared__ unsigned short HvbL[16 * 512];    // swizzled bf16
    __shared__ unsigned short GvL[16 * 512];     // swizzled bf16
    __shared__ float          MsgF[16 * 512];    // f32 mirror of Msg (exact GRU blend)
    __shared__ unsigned int   adjb[16 * 32];     // [b][u]: bit vp = edge u->vp
    __shared__ unsigned int   adjc[16 * 32];     // [b][vp]: bit u = edge u->vp (transpose)
    __shared__ int            typs[16 * 32];

    const int t    = threadIdx.x;
    const int bb   = blockIdx.x * 16;
    const int lane = t & 63, w = t >> 6;          // 16 waves
    const int c16  = lane & 15, kg = lane >> 4;

    // stage adjacency bitmask rows + types (t<512: one thread per (b,u))
    if (t < 512) {
        const int b = t >> 5, u = t & 31;
        const float* arow = adj + ((size_t)(bb + b) * NN + u) * NN;
        unsigned int bits = 0;
        #pragma unroll
        for (int vp = 0; vp < 32; vp++) bits |= (arow[vp] != 0.0f ? 1u : 0u) << vp;
        adjb[b * 32 + u] = bits;
        typs[b * 32 + u] = types[(bb + b) * NN + u];
    }
    __syncthreads();
    // transpose to column masks
    if (t < 512) {
        const int b = t >> 5, vp = t & 31;
        unsigned int m = 0;
        #pragma unroll
        for (int u = 0; u < 32; u++) m |= ((adjb[b * 32 + u] >> vp) & 1u) << u;
        adjc[b * 32 + vp] = m;
    }
    // owner init: Msg = 0 with bias-1 at k=501 (owner: b = t>>6, 8 h per thread)
    {
        const int b = t >> 6, hb8 = (t & 63) * 8;
        bf16x8 z = {0,0,0,0,0,0,0,0};
        float mf[8] = {0.f,0.f,0.f,0.f,0.f,0.f,0.f,0.f};
        if (hb8 == 496) { z[5] = (short)0x3F80; mf[5] = 1.0f; }
        *(bf16x8*)&MsgbL[idxus(b, hb8)] = z;
        #pragma unroll
        for (int x = 0; x < 8; x++) MsgF[b * KP + hb8 + x] = mf[x];
    }
    __syncthreads();

    unsigned short* Gblk = Gbuf + (size_t)blockIdx.x * NN * 16 * KP;

    for (int v = 0; v < NN; v++) {
        // ---- phase A: wave w owns h16 tiles {2w, 2w+1}, gates 0..2  (6 MFMA / kk)
        f32x4 acc[3][2];
        #pragma unroll
        for (int g = 0; g < 3; g++)
            #pragma unroll
            for (int q = 0; q < 2; q++) acc[g][q] = (f32x4){0.f,0.f,0.f,0.f};
        {
            const unsigned short* wB[3][2];
            #pragma unroll
            for (int g = 0; g < 3; g++)
                #pragma unroll
                for (int q = 0; q < 2; q++)
                    wB[g][q] = Whh + ((size_t)((g * 32 + 2 * w + q) * 16 + c16) * KP + kg * 8);
            const int aB = idxus(c16, kg * 8);
            #pragma unroll
            for (int kk = 0; kk < 16; kk++) {
                bf16x8 af = *(const bf16x8*)&MsgbL[aB ^ (kk * 32)];
                #pragma unroll
                for (int g = 0; g < 3; g++)
                    #pragma unroll
                    for (int q = 0; q < 2; q++) {
                        bf16x8 wf = *(const bf16x8*)(wB[g][q] + kk * 32);
                        acc[g][q] = __builtin_amdgcn_mfma_f32_16x16x32_bf16(af, wf, acc[g][q], 0, 0, 0);
                    }
            }
        }
        // epilogue A -> HvbL (and HvF at v=31)
        #pragma unroll
        for (int q = 0; q < 2; q++) {
            const int h = (2 * w + q) * 16 + c16;
            const bool ok = (h < HS);
            #pragma unroll
            for (int j = 0; j < 4; j++) {
                const int bl = kg * 4 + j;
                float hv = 0.0f;
                if (ok) {
                    const int typ = typs[bl * 32 + v];
                    const float gr = gi_tab[(size_t)(0 * 32 + typ) * KP + h];
                    const float gz = gi_tab[(size_t)(1 * 32 + typ) * KP + h];
                    const float gn = gi_tab[(size_t)(2 * 32 + typ) * KP + h];
                    const float hmsg = MsgF[bl * KP + h];
                    const float r = sigmoidf_(gr + acc[0][q][j]);
                    const float z = sigmoidf_(gz + acc[1][q][j]);
                    const float n = tanhf_(gn + r * acc[2][q][j]);
                    hv = (1.0f - z) * n + z * hmsg;
                }
                HvbL[idxus(bl, h)] = f2bf(hv);
                if (v == NN - 1) HvF[(size_t)(bb + bl) * KP + h] = hv;
            }
        }
        if (v == NN - 1) break;
        __syncthreads();

        // ---- phase B: wave w owns h16 tiles {2w, 2w+1}, mats 0..1  (4 MFMA / kk)
        f32x4 acc2[2][2];
        #pragma unroll
        for (int m = 0; m < 2; m++)
            #pragma unroll
            for (int q = 0; q < 2; q++) acc2[m][q] = (f32x4){0.f,0.f,0.f,0.f};
        {
            const unsigned short* wB[2][2];
            #pragma unroll
            for (int m = 0; m < 2; m++)
                #pragma unroll
                for (int q = 0; q < 2; q++)
                    wB[m][q] = Wgm + ((size_t)((m * 32 + 2 * w + q) * 16 + c16) * KP + kg * 8);
            const int aB = idxus(c16, kg * 8);
            #pragma unroll
            for (int kk = 0; kk < 16; kk++) {
                bf16x8 af = *(const bf16x8*)&HvbL[aB ^ (kk * 32)];
                #pragma unroll
                for (int m = 0; m < 2; m++)
                    #pragma unroll
                    for (int q = 0; q < 2; q++) {
                        bf16x8 wf = *(const bf16x8*)(wB[m][q] + kk * 32);
                        acc2[m][q] = __builtin_amdgcn_mfma_f32_16x16x32_bf16(af, wf, acc2[m][q], 0, 0, 0);
                    }
            }
        }
        // epilogue B -> GvL
        #pragma unroll
        for (int q = 0; q < 2; q++) {
            const int h = (2 * w + q) * 16 + c16;
            const bool ok = (h < HS);
            #pragma unroll
            for (int j = 0; j < 4; j++) {
                const int bl = kg * 4 + j;
                float gq = 0.0f;
                if (ok) {
                    const float zg = acc2[0][q][j] + idw[(size_t)(0 * 32 + v) * KP + h];
                    const float zm = acc2[1][q][j] + idw[(size_t)(1 * 32 + v) * KP + h];
                    gq = sigmoidf_(zg) * zm;
                }
                GvL[idxus(bl, h)] = f2bf(gq);
            }
        }
        __syncthreads();

        // ---- owners (b = t>>6, 8 h each): persist G_v, build Msg_{v+1} via edge list
        {
            const int b = t >> 6, hb8 = (t & 63) * 8;
            bf16x8 g = *(const bf16x8*)&GvL[idxus(b, hb8)];
            *(bf16x8*)&Gblk[(size_t)(v * 16 + b) * KP + hb8] = g;

            float msg[8] = {0.f,0.f,0.f,0.f,0.f,0.f,0.f,0.f};
            unsigned int mask = adjc[b * 32 + (v + 1)];
            if ((mask >> v) & 1u) {                 // u == v from registers
                #pragma unroll
                for (int x = 0; x < 8; x++) msg[x] += bf2f((unsigned short)g[x]);
            }
            mask &= (1u << v) - 1u;                 // u < v from global history
            while (mask) {
                const int u = __builtin_ctz(mask); mask &= mask - 1u;
                bf16x8 a = *(const bf16x8*)&Gblk[(size_t)(u * 16 + b) * KP + hb8];
                #pragma unroll
                for (int x = 0; x < 8; x++) msg[x] += bf2f((unsigned short)a[x]);
            }
            if (hb8 == 496) msg[5] = 1.0f;          // bias column k=501
            bf16x8 mb;
            #pragma unroll
            for (int x = 0; x < 8; x++) mb[x] = (short)f2bf(msg[x]);
            *(bf16x8*)&MsgbL[idxus(b, hb8)] = mb;
            #pragma unroll
            for (int x = 0; x < 8; x++) MsgF[b * KP + hb8 + x] = msg[x];
        }
        __syncthreads();
    }

    // ---- final: mu = HvF @ WregT + b_reg (block's 16 rows)
    __syncthreads();
    if (t < 512) {
        const int b = t >> 5, i = t & 31;
        float s = b_reg[i];
        const float* hp = HvF + (size_t)(bb + b) * KP;
        #pragma unroll 4
        for (int k = 0; k < KP; k++) s += hp[k] * WregT[k * 32 + i];
        out[(bb + b) * 32 + i] = s;
    }
}

extern "C" void kernel_launch(void* const* d_in, const int* in_sizes, int n_in,
                              void* d_out, int out_size, void* d_ws, size_t ws_size,
                              hipStream_t stream) {
    const int*   node_types = (const int*)  d_in[0];
    const float* adj        = (const float*)d_in[1];
    const float* Wg         = (const float*)d_in[2];
    const float* bg         = (const float*)d_in[3];
    const float* Wm         = (const float*)d_in[4];
    const float* W_ih       = (const float*)d_in[5];
    const float* b_ih       = (const float*)d_in[6];
    const float* W_hh       = (const float*)d_in[7];
    const float* b_hh       = (const float*)d_in[8];
    const float* W_reg      = (const float*)d_in[9];
    const float* b_reg      = (const float*)d_in[10];
    float* out = (float*)d_out;

    char* p = (char*)d_ws;
    unsigned short* Whh_p = (unsigned short*)p; p += (size_t)N_WHH * 2;
    unsigned short* Wgm_p = (unsigned short*)p; p += (size_t)N_WGM * 2;
    float* gi_tab = (float*)p; p += (size_t)N_GI * 4;
    float* idw    = (float*)p; p += (size_t)N_IDW * 4;
    float* WregT  = (float*)p; p += (size_t)N_WRT * 4;
    float* HvF    = (float*)p; p += (size_t)BATCH * KP * 4;
    unsigned short* Gbuf = (unsigned short*)p; p += (size_t)32 * NN * 16 * KP * 2;

    prep_kernel<<<1024, 256, 0, stream>>>(W_hh, Wg, Wm, W_ih, b_ih, b_hh, bg, W_reg,
                                          Whh_p, Wgm_p, gi_tab, idw, WregT);
    dvae_kernel<<<32, 1024, 0, stream>>>(Whh_p, Wgm_p, gi_tab, idw, WregT, b_reg,
                                         node_types, adj, Gbuf, HvF, out);
}